// Round 6
// baseline (144.331 us; speedup 1.0000x reference)
//
#include <hip/hip_runtime.h>

// Problem: x [64, 512, 512, 3] f32.  out = clip((mean_c(x) - q10)/max(q90-q10, .01), 0, 1)
// B=64, HW=262144 px/batch. 3 kernels + memset:
//   K1: stream x -> channel mean -> u16 xm (ws) + packed-u16 LDS hist -> global u32 hist
//       (explicit 1-deep software pipeline: next iter's 3 float4 loads issued
//        before current iter's compute -> 3 loads always in flight per wave)
//   K2: per-batch quantiles from 8192-bin hist
//   K3: u16 xm -> normalized f32 out

#define BINS 8192
#define PIXB 262144
#define NB 32                      // blocks per batch in K1 -> 2048 blocks
#define CHUNK (PIXB / NB)          // 8192 px/block
#define K1_ITERS (CHUNK / 1024)    // 8 iters of 4 px/thread

// ---------------- K1: fused channel-mean + histogram ----------------
__global__ __launch_bounds__(256) void k_mean_hist(const float* __restrict__ x,
                                                   unsigned short* __restrict__ xmu,
                                                   unsigned int* __restrict__ histg) {
    __shared__ unsigned int histp[BINS / 2];   // packed u16 counts, 16 KB
    const int tid = threadIdx.x;
    const int b = blockIdx.x >> 5;
    const int c = blockIdx.x & 31;

    for (int i = tid; i < BINS / 2; i += 256) histp[i] = 0;
    __syncthreads();

    const float4* __restrict__ X4 = (const float4*)x;
    uint2* __restrict__ XMU2 = (uint2*)xmu;
    const int pix0 = b * PIXB + c * CHUNK;
    const float k3 = 1.0f / 3.0f;

#define PROCESS(P, A, D, E)                                                  \
    {                                                                        \
        float s0 = ((A).x + (A).y + (A).z) * k3;                             \
        float s1 = ((A).w + (D).x + (D).y) * k3;                             \
        float s2 = ((D).z + (D).w + (E).x) * k3;                             \
        float s3 = ((E).y + (E).z + (E).w) * k3;                             \
        unsigned int q0 = (unsigned int)(s0 * 65535.0f + 0.5f);              \
        unsigned int q1 = (unsigned int)(s1 * 65535.0f + 0.5f);              \
        unsigned int q2 = (unsigned int)(s2 * 65535.0f + 0.5f);              \
        unsigned int q3 = (unsigned int)(s3 * 65535.0f + 0.5f);              \
        uint2 w;                                                             \
        w.x = q0 | (q1 << 16);                                               \
        w.y = q2 | (q3 << 16);                                               \
        XMU2[(P) >> 2] = w;                                                  \
        /* bin=q>>3; word=q>>4; half=(q>>3)&1. <=8192 adds/block: no ovfl */ \
        atomicAdd(&histp[q0 >> 4], 1u << (((q0 >> 3) & 1) * 16));            \
        atomicAdd(&histp[q1 >> 4], 1u << (((q1 >> 3) & 1) * 16));            \
        atomicAdd(&histp[q2 >> 4], 1u << (((q2 >> 3) & 1) * 16));            \
        atomicAdd(&histp[q3 >> 4], 1u << (((q3 >> 3) & 1) * 16));            \
    }

    // software pipeline: loads for it+1 issued before compute of it
    int p = pix0 + tid * 4;
    int f4 = (p * 3) >> 2;
    float4 a = X4[f4 + 0];
    float4 d = X4[f4 + 1];
    float4 e = X4[f4 + 2];
#pragma unroll
    for (int it = 0; it < K1_ITERS - 1; ++it) {
        const int pn = pix0 + (it + 1) * 1024 + tid * 4;
        const int f4n = (pn * 3) >> 2;
        float4 an = X4[f4n + 0];
        float4 dn = X4[f4n + 1];
        float4 en = X4[f4n + 2];
        PROCESS(p, a, d, e)
        a = an; d = dn; e = en; p = pn;
    }
    PROCESS(p, a, d, e)
#undef PROCESS
    __syncthreads();

    unsigned int* dst = histg + (size_t)b * BINS;
    for (int i = tid; i < BINS / 2; i += 256) {
        unsigned int w = histp[i];
        unsigned int lo16 = w & 0xffffu, hi16 = w >> 16;
        if (lo16) atomicAdd(&dst[2 * i + 0], lo16);   // device-scope
        if (hi16) atomicAdd(&dst[2 * i + 1], hi16);
    }
}

// ---------------- K2: per-batch quantiles from histogram ----------------
__global__ __launch_bounds__(256) void k_quantile(const unsigned int* __restrict__ histg,
                                                  float* __restrict__ lo_inv) {
    __shared__ unsigned int tsum[256];
    __shared__ float vals[4];
    const int b = blockIdx.x;
    const int tid = threadIdx.x;

    const uint4* __restrict__ H4 = (const uint4*)(histg + (size_t)b * BINS);
    uint4 hh[8];                               // bins [tid*32, tid*32+32)
#pragma unroll
    for (int j = 0; j < 8; ++j) hh[j] = H4[tid * 8 + j];
    unsigned int s = 0;
#pragma unroll
    for (int j = 0; j < 8; ++j) s += hh[j].x + hh[j].y + hh[j].z + hh[j].w;
    tsum[tid] = s;
    __syncthreads();
    for (int off = 1; off < 256; off <<= 1) {  // Hillis-Steele inclusive scan
        unsigned int v = tsum[tid];
        unsigned int add = (tid >= off) ? tsum[tid - off] : 0u;
        __syncthreads();
        tsum[tid] = v + add;
        __syncthreads();
    }
    unsigned int cum = (tid == 0) ? 0u : tsum[tid - 1];

    // order stats q*(n-1), n=262144: 26214.3 -> {26214,26215}, 235928.7 -> {235928,235929}
    const unsigned int T0 = 26214u, T1 = 26215u, T2 = 235928u, T3 = 235929u;
    const int base = tid * 32;
#pragma unroll
    for (int j = 0; j < 8; ++j) {
        unsigned int e4[4] = {hh[j].x, hh[j].y, hh[j].z, hh[j].w};
#pragma unroll
        for (int q = 0; q < 4; ++q) {
            unsigned int h = e4[q];
            unsigned int nc = cum + h;
            if (h) {
                float edge = (float)(base + 4 * j + q);
                float invh = 1.0f / (float)h;
#define CHECK(KT, slot)                                                     \
                if (KT >= cum && KT < nc) {                                 \
                    float r = (float)(KT - cum);                            \
                    vals[slot] = (edge + (r + 0.5f) * invh) * (1.0f / BINS);\
                }
                CHECK(T0, 0) CHECK(T1, 1) CHECK(T2, 2) CHECK(T3, 3)
#undef CHECK
            }
            cum = nc;
        }
    }
    __syncthreads();
    if (tid == 0) {
        float lo = 0.7f * vals[0] + 0.3f * vals[1];
        float hi = 0.3f * vals[2] + 0.7f * vals[3];
        float rng = fmaxf(hi - lo, 0.01f);
        lo_inv[b * 2 + 0] = lo;
        lo_inv[b * 2 + 1] = 1.0f / rng;
    }
}

// ---------------- K3: u16 xm -> normalized f32 out ----------------
__global__ __launch_bounds__(256) void k_norm(const unsigned short* __restrict__ xmu,
                                              float* __restrict__ out,
                                              const float* __restrict__ lo_inv) {
    const int i = blockIdx.x * 256 + threadIdx.x;   // 8 px/thread
    const int p = i * 8;
    const int b = p >> 18;                          // 262144 px/batch
    const float lo = lo_inv[b * 2 + 0];
    const float inv = lo_inv[b * 2 + 1];
    const float uq = 1.0f / 65535.0f;

    uint4 w = ((const uint4*)xmu)[i];               // 8 u16
    float4* __restrict__ O4 = (float4*)out;
    float4 v0, v1;
    v0.x = fminf(fmaxf(((float)(w.x & 0xffffu) * uq - lo) * inv, 0.0f), 1.0f);
    v0.y = fminf(fmaxf(((float)(w.x >> 16)     * uq - lo) * inv, 0.0f), 1.0f);
    v0.z = fminf(fmaxf(((float)(w.y & 0xffffu) * uq - lo) * inv, 0.0f), 1.0f);
    v0.w = fminf(fmaxf(((float)(w.y >> 16)     * uq - lo) * inv, 0.0f), 1.0f);
    v1.x = fminf(fmaxf(((float)(w.z & 0xffffu) * uq - lo) * inv, 0.0f), 1.0f);
    v1.y = fminf(fmaxf(((float)(w.z >> 16)     * uq - lo) * inv, 0.0f), 1.0f);
    v1.z = fminf(fmaxf(((float)(w.w & 0xffffu) * uq - lo) * inv, 0.0f), 1.0f);
    v1.w = fminf(fmaxf(((float)(w.w >> 16)     * uq - lo) * inv, 0.0f), 1.0f);
    O4[(p >> 2) + 0] = v0;
    O4[(p >> 2) + 1] = v1;
}

extern "C" void kernel_launch(void* const* d_in, const int* in_sizes, int n_in,
                              void* d_out, int out_size, void* d_ws, size_t ws_size,
                              hipStream_t stream) {
    const float* x = (const float*)d_in[0];
    float* out = (float*)d_out;

    // ws layout: [0,512B) lo_inv | [4KB, 4KB+2MB) histg | [4MB, ...) xm u16
    float* lo_inv = (float*)d_ws;
    unsigned int* histg = (unsigned int*)((char*)d_ws + 4096);
    unsigned short* xmu = (unsigned short*)((char*)d_ws + (4u << 20));

    hipMemsetAsync(histg, 0, (size_t)64 * BINS * sizeof(unsigned int), stream);

    k_mean_hist<<<64 * NB, 256, 0, stream>>>(x, xmu, histg);
    k_quantile<<<64, 256, 0, stream>>>(histg, lo_inv);
    k_norm<<<out_size / (8 * 256), 256, 0, stream>>>(xmu, out, lo_inv);
}

// Round 7
// 92.063 us; speedup vs baseline: 1.5678x; 1.5678x over previous
//
#include <hip/hip_runtime.h>

// Problem: x [64, 512, 512, 3] f32.  out = clip((mean_c(x) - q10)/max(q90-q10, .01), 0, 1)
// B=64, HW=262144 px/batch. 3 kernels + memset:
//   K1: stream x -> channel mean -> u16 xm (ws) + u32 LDS hist -> global u32 hist
//       (R2's proven plain-loop structure; compiler schedules the loads)
//   K2: per-batch quantiles from 8192-bin hist (register-resident)
//   K3: u16 xm -> normalized f32 out

#define BINS 8192
#define PIXB 262144
#define NB 16                      // blocks per batch in K1 -> 1024 blocks

// ---------------- K1: fused channel-mean + histogram (R2 structure) ----------------
__global__ __launch_bounds__(256) void k_mean_hist(const float* __restrict__ x,
                                                   unsigned short* __restrict__ xmu,
                                                   unsigned int* __restrict__ histg) {
    __shared__ unsigned int hist[BINS];        // full u32 counts, 32 KB
    const int tid = threadIdx.x;
    const int b = blockIdx.x / NB;
    const int c = blockIdx.x % NB;

    for (int i = tid; i < BINS; i += 256) hist[i] = 0;
    __syncthreads();

    const float4* __restrict__ X4 = (const float4*)x;
    uint2* __restrict__ XMU2 = (uint2*)xmu;

    const int chunk = PIXB / NB;               // 16384 px
    const int pix0 = b * PIXB + c * chunk;
    const float k3 = 1.0f / 3.0f;

    for (int it = 0; it < chunk / 1024; ++it) {   // 16 iters, 4 px/thread
        const int p = pix0 + it * 1024 + tid * 4;
        const int f4 = (p * 3) >> 2;
        float4 a = X4[f4 + 0];
        float4 d = X4[f4 + 1];
        float4 e = X4[f4 + 2];
        float s0 = (a.x + a.y + a.z) * k3;
        float s1 = (a.w + d.x + d.y) * k3;
        float s2 = (d.z + d.w + e.x) * k3;
        float s3 = (e.y + e.z + e.w) * k3;
        unsigned int q0 = (unsigned int)(s0 * 65535.0f + 0.5f);   // x<1 -> q<=65535
        unsigned int q1 = (unsigned int)(s1 * 65535.0f + 0.5f);
        unsigned int q2 = (unsigned int)(s2 * 65535.0f + 0.5f);
        unsigned int q3 = (unsigned int)(s3 * 65535.0f + 0.5f);
        uint2 w;
        w.x = q0 | (q1 << 16);
        w.y = q2 | (q3 << 16);
        XMU2[p >> 2] = w;
        atomicAdd(&hist[q0 >> 3], 1u);
        atomicAdd(&hist[q1 >> 3], 1u);
        atomicAdd(&hist[q2 >> 3], 1u);
        atomicAdd(&hist[q3 >> 3], 1u);
    }
    __syncthreads();

    unsigned int* dst = histg + (size_t)b * BINS;
    for (int i = tid; i < BINS; i += 256) {
        unsigned int v = hist[i];
        if (v) atomicAdd(&dst[i], v);          // device-scope
    }
}

// ---------------- K2: per-batch quantiles from histogram ----------------
__global__ __launch_bounds__(256) void k_quantile(const unsigned int* __restrict__ histg,
                                                  float* __restrict__ lo_inv) {
    __shared__ unsigned int tsum[256];
    __shared__ float vals[4];
    const int b = blockIdx.x;
    const int tid = threadIdx.x;

    const uint4* __restrict__ H4 = (const uint4*)(histg + (size_t)b * BINS);
    uint4 hh[8];                               // bins [tid*32, tid*32+32)
#pragma unroll
    for (int j = 0; j < 8; ++j) hh[j] = H4[tid * 8 + j];
    unsigned int s = 0;
#pragma unroll
    for (int j = 0; j < 8; ++j) s += hh[j].x + hh[j].y + hh[j].z + hh[j].w;
    tsum[tid] = s;
    __syncthreads();
    for (int off = 1; off < 256; off <<= 1) {  // Hillis-Steele inclusive scan
        unsigned int v = tsum[tid];
        unsigned int add = (tid >= off) ? tsum[tid - off] : 0u;
        __syncthreads();
        tsum[tid] = v + add;
        __syncthreads();
    }
    unsigned int cum = (tid == 0) ? 0u : tsum[tid - 1];

    // order stats q*(n-1), n=262144: 26214.3 -> {26214,26215}, 235928.7 -> {235928,235929}
    const unsigned int T0 = 26214u, T1 = 26215u, T2 = 235928u, T3 = 235929u;
    const int base = tid * 32;
#pragma unroll
    for (int j = 0; j < 8; ++j) {
        unsigned int e4[4] = {hh[j].x, hh[j].y, hh[j].z, hh[j].w};
#pragma unroll
        for (int q = 0; q < 4; ++q) {
            unsigned int h = e4[q];
            unsigned int nc = cum + h;
            if (h) {
                float edge = (float)(base + 4 * j + q);
                float invh = 1.0f / (float)h;
#define CHECK(KT, slot)                                                     \
                if (KT >= cum && KT < nc) {                                 \
                    float r = (float)(KT - cum);                            \
                    vals[slot] = (edge + (r + 0.5f) * invh) * (1.0f / BINS);\
                }
                CHECK(T0, 0) CHECK(T1, 1) CHECK(T2, 2) CHECK(T3, 3)
#undef CHECK
            }
            cum = nc;
        }
    }
    __syncthreads();
    if (tid == 0) {
        float lo = 0.7f * vals[0] + 0.3f * vals[1];
        float hi = 0.3f * vals[2] + 0.7f * vals[3];
        float rng = fmaxf(hi - lo, 0.01f);
        lo_inv[b * 2 + 0] = lo;
        lo_inv[b * 2 + 1] = 1.0f / rng;
    }
}

// ---------------- K3: u16 xm -> normalized f32 out ----------------
__global__ __launch_bounds__(256) void k_norm(const unsigned short* __restrict__ xmu,
                                              float* __restrict__ out,
                                              const float* __restrict__ lo_inv) {
    const int i = blockIdx.x * 256 + threadIdx.x;   // 8 px/thread
    const int p = i * 8;
    const int b = p >> 18;                          // 262144 px/batch
    const float lo = lo_inv[b * 2 + 0];
    const float inv = lo_inv[b * 2 + 1];
    const float uq = 1.0f / 65535.0f;

    uint4 w = ((const uint4*)xmu)[i];               // 8 u16
    float4* __restrict__ O4 = (float4*)out;
    float4 v0, v1;
    v0.x = fminf(fmaxf(((float)(w.x & 0xffffu) * uq - lo) * inv, 0.0f), 1.0f);
    v0.y = fminf(fmaxf(((float)(w.x >> 16)     * uq - lo) * inv, 0.0f), 1.0f);
    v0.z = fminf(fmaxf(((float)(w.y & 0xffffu) * uq - lo) * inv, 0.0f), 1.0f);
    v0.w = fminf(fmaxf(((float)(w.y >> 16)     * uq - lo) * inv, 0.0f), 1.0f);
    v1.x = fminf(fmaxf(((float)(w.z & 0xffffu) * uq - lo) * inv, 0.0f), 1.0f);
    v1.y = fminf(fmaxf(((float)(w.z >> 16)     * uq - lo) * inv, 0.0f), 1.0f);
    v1.z = fminf(fmaxf(((float)(w.w & 0xffffu) * uq - lo) * inv, 0.0f), 1.0f);
    v1.w = fminf(fmaxf(((float)(w.w >> 16)     * uq - lo) * inv, 0.0f), 1.0f);
    O4[(p >> 2) + 0] = v0;
    O4[(p >> 2) + 1] = v1;
}

extern "C" void kernel_launch(void* const* d_in, const int* in_sizes, int n_in,
                              void* d_out, int out_size, void* d_ws, size_t ws_size,
                              hipStream_t stream) {
    const float* x = (const float*)d_in[0];
    float* out = (float*)d_out;

    // ws layout: [0,512B) lo_inv | [4KB, 4KB+2MB) histg | [4MB, ...) xm u16
    float* lo_inv = (float*)d_ws;
    unsigned int* histg = (unsigned int*)((char*)d_ws + 4096);
    unsigned short* xmu = (unsigned short*)((char*)d_ws + (4u << 20));

    hipMemsetAsync(histg, 0, (size_t)64 * BINS * sizeof(unsigned int), stream);

    k_mean_hist<<<64 * NB, 256, 0, stream>>>(x, xmu, histg);
    k_quantile<<<64, 256, 0, stream>>>(histg, lo_inv);
    k_norm<<<out_size / (8 * 256), 256, 0, stream>>>(xmu, out, lo_inv);
}

// Round 8
// 87.655 us; speedup vs baseline: 1.6466x; 1.0503x over previous
//
#include <hip/hip_runtime.h>

// Problem: x [64, 512, 512, 3] f32.  out = clip((mean_c(x) - q10)/max(q90-q10, .01), 0, 1)
// B=64, HW=262144 px/batch. 3 kernels + memset:
//   K1: stream x -> channel mean -> u16 xm (ws) + u32 LDS hist -> global u32 hist.
//       TWO independent pixel streams per thread (2x memory-level parallelism;
//       the R6 manual pipeline regressed, this keeps the plain-loop codegen).
//   K2: per-batch quantiles from 8192-bin hist (register-resident)
//   K3: u16 xm -> normalized f32 out

#define BINS 8192
#define PIXB 262144
#define NB 16                      // chunks per batch -> 1024 blocks
#define CHUNK (PIXB / NB)          // 16384 px per block
#define HALF (CHUNK / 2)           // 8192 px per stream

// ---------------- K1: fused channel-mean + histogram ----------------
__global__ __launch_bounds__(256) void k_mean_hist(const float* __restrict__ x,
                                                   unsigned short* __restrict__ xmu,
                                                   unsigned int* __restrict__ histg) {
    __shared__ unsigned int hist[BINS];        // full u32 counts, 32 KB
    const int tid = threadIdx.x;
    const int b = blockIdx.x / NB;
    const int c = blockIdx.x % NB;

    for (int i = tid; i < BINS; i += 256) hist[i] = 0;
    __syncthreads();

    const float4* __restrict__ X4 = (const float4*)x;
    uint2* __restrict__ XMU2 = (uint2*)xmu;

    const int pix0 = b * PIXB + c * CHUNK;
    const float k3 = 1.0f / 3.0f;

    for (int it = 0; it < HALF / 1024; ++it) {   // 8 iters, 2 streams x 4 px
        const int pA = pix0 + it * 1024 + tid * 4;
        const int pB = pA + HALF;
        const int fA = (pA * 3) >> 2;
        const int fB = (pB * 3) >> 2;
        // stream A loads
        float4 a0 = X4[fA + 0];
        float4 a1 = X4[fA + 1];
        float4 a2 = X4[fA + 2];
        // stream B loads (independent -> both triplets in flight together)
        float4 b0 = X4[fB + 0];
        float4 b1 = X4[fB + 1];
        float4 b2 = X4[fB + 2];

        float sA0 = (a0.x + a0.y + a0.z) * k3;
        float sA1 = (a0.w + a1.x + a1.y) * k3;
        float sA2 = (a1.z + a1.w + a2.x) * k3;
        float sA3 = (a2.y + a2.z + a2.w) * k3;
        float sB0 = (b0.x + b0.y + b0.z) * k3;
        float sB1 = (b0.w + b1.x + b1.y) * k3;
        float sB2 = (b1.z + b1.w + b2.x) * k3;
        float sB3 = (b2.y + b2.z + b2.w) * k3;

        unsigned int qA0 = (unsigned int)(sA0 * 65535.0f + 0.5f);  // x<1 -> q<=65535
        unsigned int qA1 = (unsigned int)(sA1 * 65535.0f + 0.5f);
        unsigned int qA2 = (unsigned int)(sA2 * 65535.0f + 0.5f);
        unsigned int qA3 = (unsigned int)(sA3 * 65535.0f + 0.5f);
        unsigned int qB0 = (unsigned int)(sB0 * 65535.0f + 0.5f);
        unsigned int qB1 = (unsigned int)(sB1 * 65535.0f + 0.5f);
        unsigned int qB2 = (unsigned int)(sB2 * 65535.0f + 0.5f);
        unsigned int qB3 = (unsigned int)(sB3 * 65535.0f + 0.5f);

        uint2 wA, wB;
        wA.x = qA0 | (qA1 << 16);
        wA.y = qA2 | (qA3 << 16);
        wB.x = qB0 | (qB1 << 16);
        wB.y = qB2 | (qB3 << 16);
        XMU2[pA >> 2] = wA;
        XMU2[pB >> 2] = wB;

        atomicAdd(&hist[qA0 >> 3], 1u);
        atomicAdd(&hist[qA1 >> 3], 1u);
        atomicAdd(&hist[qA2 >> 3], 1u);
        atomicAdd(&hist[qA3 >> 3], 1u);
        atomicAdd(&hist[qB0 >> 3], 1u);
        atomicAdd(&hist[qB1 >> 3], 1u);
        atomicAdd(&hist[qB2 >> 3], 1u);
        atomicAdd(&hist[qB3 >> 3], 1u);
    }
    __syncthreads();

    unsigned int* dst = histg + (size_t)b * BINS;
    for (int i = tid; i < BINS; i += 256) {
        unsigned int v = hist[i];
        if (v) atomicAdd(&dst[i], v);          // device-scope
    }
}

// ---------------- K2: per-batch quantiles from histogram ----------------
__global__ __launch_bounds__(256) void k_quantile(const unsigned int* __restrict__ histg,
                                                  float* __restrict__ lo_inv) {
    __shared__ unsigned int tsum[256];
    __shared__ float vals[4];
    const int b = blockIdx.x;
    const int tid = threadIdx.x;

    const uint4* __restrict__ H4 = (const uint4*)(histg + (size_t)b * BINS);
    uint4 hh[8];                               // bins [tid*32, tid*32+32)
#pragma unroll
    for (int j = 0; j < 8; ++j) hh[j] = H4[tid * 8 + j];
    unsigned int s = 0;
#pragma unroll
    for (int j = 0; j < 8; ++j) s += hh[j].x + hh[j].y + hh[j].z + hh[j].w;
    tsum[tid] = s;
    __syncthreads();
    for (int off = 1; off < 256; off <<= 1) {  // Hillis-Steele inclusive scan
        unsigned int v = tsum[tid];
        unsigned int add = (tid >= off) ? tsum[tid - off] : 0u;
        __syncthreads();
        tsum[tid] = v + add;
        __syncthreads();
    }
    unsigned int cum = (tid == 0) ? 0u : tsum[tid - 1];

    // order stats q*(n-1), n=262144: 26214.3 -> {26214,26215}, 235928.7 -> {235928,235929}
    const unsigned int T0 = 26214u, T1 = 26215u, T2 = 235928u, T3 = 235929u;
    const int base = tid * 32;
#pragma unroll
    for (int j = 0; j < 8; ++j) {
        unsigned int e4[4] = {hh[j].x, hh[j].y, hh[j].z, hh[j].w};
#pragma unroll
        for (int q = 0; q < 4; ++q) {
            unsigned int h = e4[q];
            unsigned int nc = cum + h;
            if (h) {
                float edge = (float)(base + 4 * j + q);
                float invh = 1.0f / (float)h;
#define CHECK(KT, slot)                                                     \
                if (KT >= cum && KT < nc) {                                 \
                    float r = (float)(KT - cum);                            \
                    vals[slot] = (edge + (r + 0.5f) * invh) * (1.0f / BINS);\
                }
                CHECK(T0, 0) CHECK(T1, 1) CHECK(T2, 2) CHECK(T3, 3)
#undef CHECK
            }
            cum = nc;
        }
    }
    __syncthreads();
    if (tid == 0) {
        float lo = 0.7f * vals[0] + 0.3f * vals[1];
        float hi = 0.3f * vals[2] + 0.7f * vals[3];
        float rng = fmaxf(hi - lo, 0.01f);
        lo_inv[b * 2 + 0] = lo;
        lo_inv[b * 2 + 1] = 1.0f / rng;
    }
}

// ---------------- K3: u16 xm -> normalized f32 out ----------------
__global__ __launch_bounds__(256) void k_norm(const unsigned short* __restrict__ xmu,
                                              float* __restrict__ out,
                                              const float* __restrict__ lo_inv) {
    const int i = blockIdx.x * 256 + threadIdx.x;   // 8 px/thread
    const int p = i * 8;
    const int b = p >> 18;                          // 262144 px/batch
    const float lo = lo_inv[b * 2 + 0];
    const float inv = lo_inv[b * 2 + 1];
    const float uq = 1.0f / 65535.0f;

    uint4 w = ((const uint4*)xmu)[i];               // 8 u16
    float4* __restrict__ O4 = (float4*)out;
    float4 v0, v1;
    v0.x = fminf(fmaxf(((float)(w.x & 0xffffu) * uq - lo) * inv, 0.0f), 1.0f);
    v0.y = fminf(fmaxf(((float)(w.x >> 16)     * uq - lo) * inv, 0.0f), 1.0f);
    v0.z = fminf(fmaxf(((float)(w.y & 0xffffu) * uq - lo) * inv, 0.0f), 1.0f);
    v0.w = fminf(fmaxf(((float)(w.y >> 16)     * uq - lo) * inv, 0.0f), 1.0f);
    v1.x = fminf(fmaxf(((float)(w.z & 0xffffu) * uq - lo) * inv, 0.0f), 1.0f);
    v1.y = fminf(fmaxf(((float)(w.z >> 16)     * uq - lo) * inv, 0.0f), 1.0f);
    v1.z = fminf(fmaxf(((float)(w.w & 0xffffu) * uq - lo) * inv, 0.0f), 1.0f);
    v1.w = fminf(fmaxf(((float)(w.w >> 16)     * uq - lo) * inv, 0.0f), 1.0f);
    O4[(p >> 2) + 0] = v0;
    O4[(p >> 2) + 1] = v1;
}

extern "C" void kernel_launch(void* const* d_in, const int* in_sizes, int n_in,
                              void* d_out, int out_size, void* d_ws, size_t ws_size,
                              hipStream_t stream) {
    const float* x = (const float*)d_in[0];
    float* out = (float*)d_out;

    // ws layout: [0,512B) lo_inv | [4KB, 4KB+2MB) histg | [4MB, ...) xm u16
    float* lo_inv = (float*)d_ws;
    unsigned int* histg = (unsigned int*)((char*)d_ws + 4096);
    unsigned short* xmu = (unsigned short*)((char*)d_ws + (4u << 20));

    hipMemsetAsync(histg, 0, (size_t)64 * BINS * sizeof(unsigned int), stream);

    k_mean_hist<<<64 * NB, 256, 0, stream>>>(x, xmu, histg);
    k_quantile<<<64, 256, 0, stream>>>(histg, lo_inv);
    k_norm<<<out_size / (8 * 256), 256, 0, stream>>>(xmu, out, lo_inv);
}

// Round 10
// 86.650 us; speedup vs baseline: 1.6657x; 1.0116x over previous
//
#include <hip/hip_runtime.h>

// Problem: x [64, 512, 512, 3] f32.  out = clip((mean_c(x) - q10)/max(q90-q10, .01), 0, 1)
// B=64, HW=262144 px/batch. 3 kernels + memset:
//   K1: stream x -> channel mean -> u16 xm (ws) + u32 LDS hist -> global u32 hist.
//       FOUR independent pixel streams per thread (12 float4 loads in flight).
//   K2: per-batch quantiles from 8192-bin hist (register-resident)
//   K3: u16 xm -> normalized f32 out (non-temporal stores keep x L3-resident)

#define BINS 8192
#define PIXB 262144
#define NB 16                      // chunks per batch -> 1024 blocks
#define CHUNK (PIXB / NB)          // 16384 px per block
#define QTR (CHUNK / 4)            // 4096 px per stream

typedef float vf4 __attribute__((ext_vector_type(4)));   // native vec for NT store

// ---------------- K1: fused channel-mean + histogram ----------------
__global__ __launch_bounds__(256) void k_mean_hist(const float* __restrict__ x,
                                                   unsigned short* __restrict__ xmu,
                                                   unsigned int* __restrict__ histg) {
    __shared__ unsigned int hist[BINS];        // full u32 counts, 32 KB
    const int tid = threadIdx.x;
    const int b = blockIdx.x / NB;
    const int c = blockIdx.x % NB;

    for (int i = tid; i < BINS; i += 256) hist[i] = 0;
    __syncthreads();

    const float4* __restrict__ X4 = (const float4*)x;
    uint2* __restrict__ XMU2 = (uint2*)xmu;

    const int pix0 = b * PIXB + c * CHUNK;
    const float k3 = 1.0f / 3.0f;

    for (int it = 0; it < QTR / 1024; ++it) {   // 4 iters, 4 streams x 4 px
        const int pA = pix0 + it * 1024 + tid * 4;
        const int pB = pA + QTR;
        const int pC = pA + 2 * QTR;
        const int pD = pA + 3 * QTR;
        const int fA = (pA * 3) >> 2;
        const int fB = (pB * 3) >> 2;
        const int fC = (pC * 3) >> 2;
        const int fD = (pD * 3) >> 2;
        // 12 independent float4 loads -> all in flight together
        float4 a0 = X4[fA + 0];
        float4 a1 = X4[fA + 1];
        float4 a2 = X4[fA + 2];
        float4 b0 = X4[fB + 0];
        float4 b1 = X4[fB + 1];
        float4 b2 = X4[fB + 2];
        float4 c0 = X4[fC + 0];
        float4 c1 = X4[fC + 1];
        float4 c2 = X4[fC + 2];
        float4 d0 = X4[fD + 0];
        float4 d1 = X4[fD + 1];
        float4 d2 = X4[fD + 2];

        float sA0 = (a0.x + a0.y + a0.z) * k3;
        float sA1 = (a0.w + a1.x + a1.y) * k3;
        float sA2 = (a1.z + a1.w + a2.x) * k3;
        float sA3 = (a2.y + a2.z + a2.w) * k3;
        float sB0 = (b0.x + b0.y + b0.z) * k3;
        float sB1 = (b0.w + b1.x + b1.y) * k3;
        float sB2 = (b1.z + b1.w + b2.x) * k3;
        float sB3 = (b2.y + b2.z + b2.w) * k3;
        float sC0 = (c0.x + c0.y + c0.z) * k3;
        float sC1 = (c0.w + c1.x + c1.y) * k3;
        float sC2 = (c1.z + c1.w + c2.x) * k3;
        float sC3 = (c2.y + c2.z + c2.w) * k3;
        float sD0 = (d0.x + d0.y + d0.z) * k3;
        float sD1 = (d0.w + d1.x + d1.y) * k3;
        float sD2 = (d1.z + d1.w + d2.x) * k3;
        float sD3 = (d2.y + d2.z + d2.w) * k3;

        unsigned int qA0 = (unsigned int)(sA0 * 65535.0f + 0.5f);  // x<1 -> q<=65535
        unsigned int qA1 = (unsigned int)(sA1 * 65535.0f + 0.5f);
        unsigned int qA2 = (unsigned int)(sA2 * 65535.0f + 0.5f);
        unsigned int qA3 = (unsigned int)(sA3 * 65535.0f + 0.5f);
        unsigned int qB0 = (unsigned int)(sB0 * 65535.0f + 0.5f);
        unsigned int qB1 = (unsigned int)(sB1 * 65535.0f + 0.5f);
        unsigned int qB2 = (unsigned int)(sB2 * 65535.0f + 0.5f);
        unsigned int qB3 = (unsigned int)(sB3 * 65535.0f + 0.5f);
        unsigned int qC0 = (unsigned int)(sC0 * 65535.0f + 0.5f);
        unsigned int qC1 = (unsigned int)(sC1 * 65535.0f + 0.5f);
        unsigned int qC2 = (unsigned int)(sC2 * 65535.0f + 0.5f);
        unsigned int qC3 = (unsigned int)(sC3 * 65535.0f + 0.5f);
        unsigned int qD0 = (unsigned int)(sD0 * 65535.0f + 0.5f);
        unsigned int qD1 = (unsigned int)(sD1 * 65535.0f + 0.5f);
        unsigned int qD2 = (unsigned int)(sD2 * 65535.0f + 0.5f);
        unsigned int qD3 = (unsigned int)(sD3 * 65535.0f + 0.5f);

        uint2 wA, wB, wC, wD;
        wA.x = qA0 | (qA1 << 16);  wA.y = qA2 | (qA3 << 16);
        wB.x = qB0 | (qB1 << 16);  wB.y = qB2 | (qB3 << 16);
        wC.x = qC0 | (qC1 << 16);  wC.y = qC2 | (qC3 << 16);
        wD.x = qD0 | (qD1 << 16);  wD.y = qD2 | (qD3 << 16);
        XMU2[pA >> 2] = wA;
        XMU2[pB >> 2] = wB;
        XMU2[pC >> 2] = wC;
        XMU2[pD >> 2] = wD;

        atomicAdd(&hist[qA0 >> 3], 1u);
        atomicAdd(&hist[qA1 >> 3], 1u);
        atomicAdd(&hist[qA2 >> 3], 1u);
        atomicAdd(&hist[qA3 >> 3], 1u);
        atomicAdd(&hist[qB0 >> 3], 1u);
        atomicAdd(&hist[qB1 >> 3], 1u);
        atomicAdd(&hist[qB2 >> 3], 1u);
        atomicAdd(&hist[qB3 >> 3], 1u);
        atomicAdd(&hist[qC0 >> 3], 1u);
        atomicAdd(&hist[qC1 >> 3], 1u);
        atomicAdd(&hist[qC2 >> 3], 1u);
        atomicAdd(&hist[qC3 >> 3], 1u);
        atomicAdd(&hist[qD0 >> 3], 1u);
        atomicAdd(&hist[qD1 >> 3], 1u);
        atomicAdd(&hist[qD2 >> 3], 1u);
        atomicAdd(&hist[qD3 >> 3], 1u);
    }
    __syncthreads();

    unsigned int* dst = histg + (size_t)b * BINS;
    for (int i = tid; i < BINS; i += 256) {
        unsigned int v = hist[i];
        if (v) atomicAdd(&dst[i], v);          // device-scope
    }
}

// ---------------- K2: per-batch quantiles from histogram ----------------
__global__ __launch_bounds__(256) void k_quantile(const unsigned int* __restrict__ histg,
                                                  float* __restrict__ lo_inv) {
    __shared__ unsigned int tsum[256];
    __shared__ float vals[4];
    const int b = blockIdx.x;
    const int tid = threadIdx.x;

    const uint4* __restrict__ H4 = (const uint4*)(histg + (size_t)b * BINS);
    uint4 hh[8];                               // bins [tid*32, tid*32+32)
#pragma unroll
    for (int j = 0; j < 8; ++j) hh[j] = H4[tid * 8 + j];
    unsigned int s = 0;
#pragma unroll
    for (int j = 0; j < 8; ++j) s += hh[j].x + hh[j].y + hh[j].z + hh[j].w;
    tsum[tid] = s;
    __syncthreads();
    for (int off = 1; off < 256; off <<= 1) {  // Hillis-Steele inclusive scan
        unsigned int v = tsum[tid];
        unsigned int add = (tid >= off) ? tsum[tid - off] : 0u;
        __syncthreads();
        tsum[tid] = v + add;
        __syncthreads();
    }
    unsigned int cum = (tid == 0) ? 0u : tsum[tid - 1];

    // order stats q*(n-1), n=262144: 26214.3 -> {26214,26215}, 235928.7 -> {235928,235929}
    const unsigned int T0 = 26214u, T1 = 26215u, T2 = 235928u, T3 = 235929u;
    const int base = tid * 32;
#pragma unroll
    for (int j = 0; j < 8; ++j) {
        unsigned int e4[4] = {hh[j].x, hh[j].y, hh[j].z, hh[j].w};
#pragma unroll
        for (int q = 0; q < 4; ++q) {
            unsigned int h = e4[q];
            unsigned int nc = cum + h;
            if (h) {
                float edge = (float)(base + 4 * j + q);
                float invh = 1.0f / (float)h;
#define CHECK(KT, slot)                                                     \
                if (KT >= cum && KT < nc) {                                 \
                    float r = (float)(KT - cum);                            \
                    vals[slot] = (edge + (r + 0.5f) * invh) * (1.0f / BINS);\
                }
                CHECK(T0, 0) CHECK(T1, 1) CHECK(T2, 2) CHECK(T3, 3)
#undef CHECK
            }
            cum = nc;
        }
    }
    __syncthreads();
    if (tid == 0) {
        float lo = 0.7f * vals[0] + 0.3f * vals[1];
        float hi = 0.3f * vals[2] + 0.7f * vals[3];
        float rng = fmaxf(hi - lo, 0.01f);
        lo_inv[b * 2 + 0] = lo;
        lo_inv[b * 2 + 1] = 1.0f / rng;
    }
}

// ---------------- K3: u16 xm -> normalized f32 out ----------------
__global__ __launch_bounds__(256) void k_norm(const unsigned short* __restrict__ xmu,
                                              float* __restrict__ out,
                                              const float* __restrict__ lo_inv) {
    const int i = blockIdx.x * 256 + threadIdx.x;   // 8 px/thread
    const int p = i * 8;
    const int b = p >> 18;                          // 262144 px/batch
    const float lo = lo_inv[b * 2 + 0];
    const float inv = lo_inv[b * 2 + 1];
    const float uq = 1.0f / 65535.0f;

    uint4 w = ((const uint4*)xmu)[i];               // 8 u16
    vf4* __restrict__ O4 = (vf4*)out;
    vf4 v0, v1;
    v0.x = fminf(fmaxf(((float)(w.x & 0xffffu) * uq - lo) * inv, 0.0f), 1.0f);
    v0.y = fminf(fmaxf(((float)(w.x >> 16)     * uq - lo) * inv, 0.0f), 1.0f);
    v0.z = fminf(fmaxf(((float)(w.y & 0xffffu) * uq - lo) * inv, 0.0f), 1.0f);
    v0.w = fminf(fmaxf(((float)(w.y >> 16)     * uq - lo) * inv, 0.0f), 1.0f);
    v1.x = fminf(fmaxf(((float)(w.z & 0xffffu) * uq - lo) * inv, 0.0f), 1.0f);
    v1.y = fminf(fmaxf(((float)(w.z >> 16)     * uq - lo) * inv, 0.0f), 1.0f);
    v1.z = fminf(fmaxf(((float)(w.w & 0xffffu) * uq - lo) * inv, 0.0f), 1.0f);
    v1.w = fminf(fmaxf(((float)(w.w >> 16)     * uq - lo) * inv, 0.0f), 1.0f);
    // non-temporal: out is write-once -> don't evict x from L2/L3
    __builtin_nontemporal_store(v0, &O4[(p >> 2) + 0]);
    __builtin_nontemporal_store(v1, &O4[(p >> 2) + 1]);
}

extern "C" void kernel_launch(void* const* d_in, const int* in_sizes, int n_in,
                              void* d_out, int out_size, void* d_ws, size_t ws_size,
                              hipStream_t stream) {
    const float* x = (const float*)d_in[0];
    float* out = (float*)d_out;

    // ws layout: [0,512B) lo_inv | [4KB, 4KB+2MB) histg | [4MB, ...) xm u16
    float* lo_inv = (float*)d_ws;
    unsigned int* histg = (unsigned int*)((char*)d_ws + 4096);
    unsigned short* xmu = (unsigned short*)((char*)d_ws + (4u << 20));

    (void)hipMemsetAsync(histg, 0, (size_t)64 * BINS * sizeof(unsigned int), stream);

    k_mean_hist<<<64 * NB, 256, 0, stream>>>(x, xmu, histg);
    k_quantile<<<64, 256, 0, stream>>>(histg, lo_inv);
    k_norm<<<out_size / (8 * 256), 256, 0, stream>>>(xmu, out, lo_inv);
}